// Round 14
// baseline (292.503 us; speedup 1.0000x reference)
//
#include <hip/hip_runtime.h>
#include <math.h>

#define BB 16
#define AA 128
#define NNB 127
#define FF 128
#define GG 25

typedef __attribute__((ext_vector_type(8))) short bf16x8;
typedef __attribute__((ext_vector_type(4))) float f32x4;
typedef unsigned short ushort_t;

#define GLOBAL_LOAD_LDS16(gp, lp)                                                        \
    __builtin_amdgcn_global_load_lds((const __attribute__((address_space(1))) unsigned int*)(gp), \
                                     (__attribute__((address_space(3))) unsigned int*)(lp), 16, 0, 0)

__device__ __forceinline__ float ssp_f(float x) {
    return fmaxf(x, 0.f) + log1pf(__expf(-fabsf(x))) - 0.6931471805599453f;
}

// softplus(x)-ln2 with poly log1p: 1 trans op. |err| <= ~1e-5
__device__ __forceinline__ float ssp_fast(float x) {
    float e = __expf(-fabsf(x));
    float p = fmaf(e, 0.03215845f, -0.13606275f);
    p = fmaf(e, p, 0.28947478f);
    p = fmaf(e, p, -0.49190896f);
    p = fmaf(e, p, 0.99949556f);
    return fmaxf(x, 0.f) + e * p - 0.6931471805599453f;
}

__device__ __forceinline__ ushort_t f2bf(float f) {
    unsigned int u = __float_as_uint(f);
    unsigned int r = (u + 0x7fffu + ((u >> 16) & 1u)) >> 16;
    return (ushort_t)r;
}

__device__ __forceinline__ float bf2f(ushort_t h) {
    return __uint_as_float(((unsigned int)h) << 16);
}

// round-half-up bf16 pair pack: 2 adds + 1 v_perm. err <= 0.5 ulp.
__device__ __forceinline__ unsigned int pack2bf_rhu(float lo, float hi) {
    return __builtin_amdgcn_perm(__float_as_uint(hi) + 0x8000u,
                                 __float_as_uint(lo) + 0x8000u, 0x07060302u);
}

// y column permutation: f and f+16 become adjacent -> float2 epilogue loads
__device__ __forceinline__ int yperm(int f) {
    return (f & ~31) + ((f & 15) << 1) + ((f >> 4) & 1);
}

// ---- fused setup: geometry + weight prep + x init ----
__global__ __launch_bounds__(256) void k_setup(
    const float* __restrict__ positions, const float* __restrict__ cell,
    const float* __restrict__ cell_offset, const float* __restrict__ nmask,
    const int* __restrict__ neighbors,
    const float* __restrict__ W1, const float* __restrict__ W2,
    const float* __restrict__ Win, const float* __restrict__ Wf, const float* __restrict__ Wd,
    const float* __restrict__ emb, const int* __restrict__ z,
    float* __restrict__ r_g, float* __restrict__ cm_g,
    ushort_t* __restrict__ w1t, ushort_t* __restrict__ w2f,
    ushort_t* __restrict__ whi, ushort_t* __restrict__ wlo,
    float* __restrict__ x) {
    int i = blockIdx.x * 256 + threadIdx.x;
    if (i < BB * AA * 128) {
        int row = i >> 7, n = i & 127;
        if (n < NNB) {
            int b = row >> 7;
            int nb = neighbors[row * NNB + n];
            float px = positions[row * 3 + 0], py = positions[row * 3 + 1], pz = positions[row * 3 + 2];
            int nrow = b * AA + nb;
            float qx = positions[nrow * 3 + 0], qy = positions[nrow * 3 + 1], qz = positions[nrow * 3 + 2];
            const float* co = cell_offset + (size_t)row * NNB * 3 + (size_t)n * 3;
            const float* cl = cell + b * 9;
            float c0 = co[0], c1 = co[1], c2 = co[2];
            float ox = c0 * cl[0] + c1 * cl[3] + c2 * cl[6];
            float oy = c0 * cl[1] + c1 * cl[4] + c2 * cl[7];
            float oz = c0 * cl[2] + c1 * cl[5] + c2 * cl[8];
            float dx = qx - px + ox, dy = qy - py + oy, dz = qz - pz + oz;
            float d2 = dx * dx + dy * dy + dz * dz;
            float mk = nmask[row * NNB + n];
            float r = (mk > 0.f) ? sqrtf(d2) : 0.f;
            float Cc = 0.5f * (__cosf(r * (3.14159265358979323846f / 5.0f)) + 1.f);
            Cc = (r < 5.0f) ? Cc : 0.f;
            r_g[i] = r;
            cm_g[i] = Cc * mk;
        } else {
            r_g[i] = 1e9f;   // exp underflows to 0 in phase 1
            cm_g[i] = 0.f;
        }
        int f = i & 127;
        x[i] = emb[z[i >> 7] * FF + f];
    }
    if (i < 3 * 128 * 32) {
        int l = i >> 12, rem = i & 4095, f = rem >> 5, g = rem & 31;
        float v = (g < GG) ? W1[l * GG * FF + g * FF + f] : 0.f;
        w1t[i] = f2bf(v);
    }
    if (i < 3 * 16384) {
        // W2 fragment-ordered: unit u = ((ks*8 + wcft)*64 + lane), 8 bf16 each.
        int l = i >> 14, e = i & 16383;
        int u = e >> 3, j = e & 7;
        int ks = u >> 9, rem = u & 511;
        int wcft = rem >> 6, lane = rem & 63;
        int f = (wcft >> 1) * 32 + (wcft & 1) * 16 + (lane & 15);
        int k = ks * 32 + (lane >> 4) * 8 + j;
        w2f[i] = f2bf(W2[l * 16384 + k * 128 + f]);
    }
    if (i < 9 * 16384) {
        int m = i / 49152;
        int rem = i - m * 49152;
        int l = rem >> 14;
        int rk = rem & 16383;
        int f = rk >> 7, k = rk & 127;
        const float* src = (m == 0) ? Win : ((m == 1) ? Wf : Wd);
        float v = src[l * 16384 + k * 128 + f];
        ushort_t h = f2bf(v);
        whi[i] = h;
        wlo[i] = f2bf(v - bf2f(h));
    }
}

// ---- fused row-GEMM kernel: G1 ts=ssp(agg@Wf+bf); G2 xn=x+ts@Wd+bd; G3 y=xn@Win (permuted) ----
__global__ __launch_bounds__(512) void k_ffn(
    const float* __restrict__ agg, const float* __restrict__ x_in,
    float* __restrict__ x_out, float* __restrict__ y, float* __restrict__ out,
    const ushort_t* __restrict__ wfh, const ushort_t* __restrict__ wfl, const float* __restrict__ bfv_g,
    const ushort_t* __restrict__ wdh, const ushort_t* __restrict__ wdl, const float* __restrict__ bdv_g,
    const ushort_t* __restrict__ wih, const ushort_t* __restrict__ wil,
    int mode) {
    __shared__ ushort_t tsh[8][136];
    __shared__ ushort_t tsl[8][136];
    const int t = threadIdx.x;
    const int lane = t & 63, w = t >> 6;
    const int l15 = lane & 15, l4 = lane >> 4;
    const int r0 = blockIdx.x << 3;
    const int fcol = (w << 4) + l15;

    bf16x8 Ah[4], Al[4];

    auto loadA_global = [&](const float* __restrict__ M) {
#pragma unroll
        for (int ks = 0; ks < 4; ++ks) {
            float v[8];
            if (l15 < 8) {
                const float4* p = (const float4*)(M + ((size_t)(r0 + l15) << 7) + (ks << 5) + (l4 << 3));
                float4 a = p[0], b = p[1];
                v[0] = a.x; v[1] = a.y; v[2] = a.z; v[3] = a.w;
                v[4] = b.x; v[5] = b.y; v[6] = b.z; v[7] = b.w;
            } else {
#pragma unroll
                for (int j = 0; j < 8; ++j) v[j] = 0.f;
            }
#pragma unroll
            for (int j = 0; j < 8; ++j) {
                ushort_t h = f2bf(v[j]);
                Ah[ks][j] = (short)h;
                Al[ks][j] = (short)f2bf(v[j] - bf2f(h));
            }
        }
    };
    auto loadA_lds = [&]() {
#pragma unroll
        for (int ks = 0; ks < 4; ++ks) {
            if (l15 < 8) {
                const char* base = (const char*)&tsh[l15][0] + (ks << 6) + (l4 << 4);
                Ah[ks] = *(const bf16x8*)base;
                const char* basel = (const char*)&tsl[l15][0] + (ks << 6) + (l4 << 4);
                Al[ks] = *(const bf16x8*)basel;
            } else {
#pragma unroll
                for (int j = 0; j < 8; ++j) { Ah[ks][j] = 0; Al[ks][j] = 0; }
            }
        }
    };

    if (mode & 1) {
        loadA_global(agg);
        float bfv = bfv_g[fcol];
        f32x4 acc = {bfv, bfv, bfv, bfv};
#pragma unroll
        for (int ks = 0; ks < 4; ++ks) {
            const bf16x8 Bh = *(const bf16x8*)(wfh + ((size_t)fcol << 7) + (ks << 5) + (l4 << 3));
            const bf16x8 Bl = *(const bf16x8*)(wfl + ((size_t)fcol << 7) + (ks << 5) + (l4 << 3));
            acc = __builtin_amdgcn_mfma_f32_16x16x32_bf16(Al[ks], Bh, acc, 0, 0, 0);
            acc = __builtin_amdgcn_mfma_f32_16x16x32_bf16(Ah[ks], Bl, acc, 0, 0, 0);
            acc = __builtin_amdgcn_mfma_f32_16x16x32_bf16(Ah[ks], Bh, acc, 0, 0, 0);
        }
#pragma unroll
        for (int reg = 0; reg < 4; ++reg) {
            int r = (l4 << 2) + reg;
            if (r < 8) {
                float v = ssp_f(acc[reg]);
                ushort_t h = f2bf(v);
                tsh[r][fcol] = h;
                tsl[r][fcol] = f2bf(v - bf2f(h));
            }
        }
        __syncthreads();
        loadA_lds();
        float bdv = bdv_g[fcol];
        f32x4 acc2 = {bdv, bdv, bdv, bdv};
#pragma unroll
        for (int ks = 0; ks < 4; ++ks) {
            const bf16x8 Bh = *(const bf16x8*)(wdh + ((size_t)fcol << 7) + (ks << 5) + (l4 << 3));
            const bf16x8 Bl = *(const bf16x8*)(wdl + ((size_t)fcol << 7) + (ks << 5) + (l4 << 3));
            acc2 = __builtin_amdgcn_mfma_f32_16x16x32_bf16(Al[ks], Bh, acc2, 0, 0, 0);
            acc2 = __builtin_amdgcn_mfma_f32_16x16x32_bf16(Ah[ks], Bl, acc2, 0, 0, 0);
            acc2 = __builtin_amdgcn_mfma_f32_16x16x32_bf16(Ah[ks], Bh, acc2, 0, 0, 0);
        }
        __syncthreads();
#pragma unroll
        for (int reg = 0; reg < 4; ++reg) {
            int r = (l4 << 2) + reg;
            if (r < 8) {
                size_t gi = ((size_t)(r0 + r) << 7) + fcol;
                float xn = x_in[gi] + acc2[reg];
                x_out[gi] = xn;
                if (mode & 4) out[gi] = xn;
                if (mode & 2) {
                    ushort_t h = f2bf(xn);
                    tsh[r][fcol] = h;
                    tsl[r][fcol] = f2bf(xn - bf2f(h));
                }
            }
        }
        if (mode & 2) __syncthreads();
    }
    if (mode & 2) {
        if (mode & 1) loadA_lds(); else loadA_global(x_in);
        f32x4 acc3 = {0.f, 0.f, 0.f, 0.f};
#pragma unroll
        for (int ks = 0; ks < 4; ++ks) {
            const bf16x8 Bh = *(const bf16x8*)(wih + ((size_t)fcol << 7) + (ks << 5) + (l4 << 3));
            const bf16x8 Bl = *(const bf16x8*)(wil + ((size_t)fcol << 7) + (ks << 5) + (l4 << 3));
            acc3 = __builtin_amdgcn_mfma_f32_16x16x32_bf16(Al[ks], Bh, acc3, 0, 0, 0);
            acc3 = __builtin_amdgcn_mfma_f32_16x16x32_bf16(Ah[ks], Bl, acc3, 0, 0, 0);
            acc3 = __builtin_amdgcn_mfma_f32_16x16x32_bf16(Ah[ks], Bh, acc3, 0, 0, 0);
        }
        const int pf = yperm(fcol);
#pragma unroll
        for (int reg = 0; reg < 4; ++reg) {
            int r = (l4 << 2) + reg;
            if (r < 8) y[((size_t)(r0 + r) << 7) + pf] = acc3[reg];
        }
    }
}

// LDS layout (dynamic, 47104 B), 2 atoms/block:
//  [0,32768)      h bf16 [128n][128f], swizzled: byte = n*256 + ((f*2) ^ ((n&7)<<4))
//  [32768,36864)  red: 8 waves x 128 f32, swizzled (disjoint from h)
//  [36864,45056)  w1t LDS copy (8 KB, linear)
//  [45056,46080)  cm f32[2][128]; [46080,47104) nbr i32[2][128]
#define SMEM_BYTES 47104

__global__ __launch_bounds__(512, 6) void k_cfconv(
    const float* __restrict__ r_g, const float* __restrict__ cm_g,
    const int* __restrict__ neighbors,
    const ushort_t* __restrict__ w1t, const float* __restrict__ b1,
    const ushort_t* __restrict__ w2f, const float* __restrict__ b2,
    const float* __restrict__ y, float* __restrict__ agg) {
    extern __shared__ char smem[];
    float* red_s = (float*)(smem + 32768);
    float* cm_s = (float*)(smem + 45056);
    int* nbr_s = (int*)(smem + 46080);

    const int row0 = blockIdx.x << 1;
    const int b = row0 >> 7;
    const int t = threadIdx.x;
    const int lane = t & 63, w = t >> 6;       // 8 waves
    const int l15 = lane & 15, l4 = lane >> 4;
    const int wr = w >> 2, wc = w & 3;

    // -- async w1t -> LDS (8 KB, one 1-KiB chunk per wave) --
    GLOBAL_LOAD_LDS16((const char*)w1t + (w << 10) + (lane << 4), smem + 36864 + (w << 10));

    // -- W2 fragments + b1 rows into regs ONCE (reused by both atoms) --
    bf16x8 w2r[8];
#pragma unroll
    for (int ks = 0; ks < 4; ++ks) {
#pragma unroll
        for (int ft = 0; ft < 2; ++ft)
            w2r[(ks << 1) + ft] = *(const bf16x8*)(w2f + ((((ks << 3) + (wc << 1) + ft) << 6) + lane) * 8);
    }
    f32x4 b1r[8];
#pragma unroll
    for (int ft = 0; ft < 8; ++ft) b1r[ft] = *(const f32x4*)(b1 + (ft << 4) + (l4 << 2));
    const float b2v0 = b2[(wc << 5) + l15];
    const float b2v1 = b2[(wc << 5) + 16 + l15];

    // -- cm/nbr for both atoms --
    if (t < 256) {
        int a = t >> 7, n = t & 127;
        cm_s[(a << 7) + n] = cm_g[((size_t)(row0 + a) << 7) + n];
        nbr_s[(a << 7) + n] = (n < NNB) ? neighbors[(row0 + a) * NNB + n] : 0;
    }
    __syncthreads();   // w1t in LDS (vmcnt drained), cm/nbr visible

#pragma unroll
    for (int a = 0; a < 2; ++a) {
        const int row = row0 + a;
        // -- phase 1: fij in regs; D[f][n] = W1T(lds) * fijT; ssp; swizzled h write --
        {
            const int nrow = (w << 4) + l15;
            const float rv = r_g[((size_t)row << 7) + nrow];
            const float width = 5.0f / (GG - 1);
            const float coeff = -0.5f / (width * width);
            float fv[8];
#pragma unroll
            for (int j = 0; j < 8; ++j) {
                int g = (l4 << 3) + j;
                float d = rv - g * width;
                fv[j] = (g < GG) ? __expf(coeff * d * d) : 0.f;   // rv=1e9 pad underflows to 0
            }
            bf16x8 fb;
            unsigned int* fbu = (unsigned int*)&fb;
            fbu[0] = pack2bf_rhu(fv[0], fv[1]);
            fbu[1] = pack2bf_rhu(fv[2], fv[3]);
            fbu[2] = pack2bf_rhu(fv[4], fv[5]);
            fbu[3] = pack2bf_rhu(fv[6], fv[7]);
            const int base = nrow * 256;
            const int sw = (nrow & 7) << 4;
#pragma unroll
            for (int ft = 0; ft < 8; ++ft) {
                bf16x8 aw = *(const bf16x8*)(smem + 36864 + ((((ft << 4) + l15)) << 6) + (l4 << 4));
                const int f0 = (ft << 4) + (l4 << 2);
                f32x4 d = __builtin_amdgcn_mfma_f32_16x16x32_bf16(aw, fb, b1r[ft], 0, 0, 0);
                unsigned int lo32 = pack2bf_rhu(ssp_fast(d[0]), ssp_fast(d[1]));
                unsigned int hi32 = pack2bf_rhu(ssp_fast(d[2]), ssp_fast(d[3]));
                unsigned long long pk = (unsigned long long)lo32 | ((unsigned long long)hi32 << 32);
                *(unsigned long long*)(smem + base + ((f0 << 1) ^ sw)) = pk;
            }
        }
        __syncthreads();   // h ready

        // -- phase 2: wave (wr,wc) = 64n x 32f; B-frags already in regs --
        f32x4 acc[4][2];
#pragma unroll
        for (int mi = 0; mi < 4; ++mi) {
            f32x4 c00 = {b2v0, b2v0, b2v0, b2v0};
            f32x4 c01 = {b2v1, b2v1, b2v1, b2v1};
            acc[mi][0] = c00;
            acc[mi][1] = c01;
        }
#pragma unroll
        for (int ks = 0; ks < 4; ++ks) {
            bf16x8 ha[4];
#pragma unroll
            for (int mi = 0; mi < 4; ++mi) {
                int n = (wr << 6) + (mi << 4) + l15;
                ha[mi] = *(const bf16x8*)(smem + n * 256 + ((((ks << 2) + l4) << 4) ^ ((n & 7) << 4)));
            }
#pragma unroll
            for (int mi = 0; mi < 4; ++mi) {
                acc[mi][0] = __builtin_amdgcn_mfma_f32_16x16x32_bf16(ha[mi], w2r[(ks << 1)], acc[mi][0], 0, 0, 0);
                acc[mi][1] = __builtin_amdgcn_mfma_f32_16x16x32_bf16(ha[mi], w2r[(ks << 1) + 1], acc[mi][1], 0, 0, 0);
            }
        }
        __syncthreads();   // h reads done (next atom may overwrite h)

        // -- epilogue: permuted-y float2 gathers; vector cm/nbr reads --
        float part0 = 0.f, part1 = 0.f;
        const float* ybase = y + ((size_t)(b * AA) << 7) + (wc << 5) + (l15 << 1);
#pragma unroll
        for (int mi = 0; mi < 4; ++mi) {
            int n0 = (wr << 6) + (mi << 4) + (l4 << 2);
            float4 cmv = *(const float4*)(cm_s + (a << 7) + n0);
            int4 nb4 = *(const int4*)(nbr_s + (a << 7) + n0);
            float2 y0 = *(const float2*)(ybase + ((size_t)nb4.x << 7));
            float2 y1 = *(const float2*)(ybase + ((size_t)nb4.y << 7));
            float2 y2 = *(const float2*)(ybase + ((size_t)nb4.z << 7));
            float2 y3 = *(const float2*)(ybase + ((size_t)nb4.w << 7));
            part0 = fmaf(y0.x, acc[mi][0][0] * cmv.x, part0);
            part1 = fmaf(y0.y, acc[mi][1][0] * cmv.x, part1);
            part0 = fmaf(y1.x, acc[mi][0][1] * cmv.y, part0);
            part1 = fmaf(y1.y, acc[mi][1][1] * cmv.y, part1);
            part0 = fmaf(y2.x, acc[mi][0][2] * cmv.z, part0);
            part1 = fmaf(y2.y, acc[mi][1][2] * cmv.z, part1);
            part0 = fmaf(y3.x, acc[mi][0][3] * cmv.w, part0);
            part1 = fmaf(y3.y, acc[mi][1][3] * cmv.w, part1);
        }
        {
            int xg = l4 << 3;
            red_s[(w << 7) + (l4 << 5) + (l15 ^ xg)] = part0;
            red_s[(w << 7) + (l4 << 5) + ((16 + l15) ^ xg)] = part1;
        }
        __syncthreads();   // red ready
        if (t < FF) {
            int wcf = t >> 5, fl = t & 31;
            float s = 0.f;
#pragma unroll
            for (int wr2 = 0; wr2 < 2; ++wr2)
#pragma unroll
                for (int g = 0; g < 4; ++g)
                    s += red_s[(((wr2 << 2) + wcf) << 7) + (g << 5) + (fl ^ (g << 3))];
            agg[(size_t)row * FF + t] = s;
        }
        // next atom's phase-1 h writes don't touch red_s (disjoint); h reads synced above
    }
}

extern "C" void kernel_launch(void* const* d_in, const int* in_sizes, int n_in,
                              void* d_out, int out_size, void* d_ws, size_t ws_size,
                              hipStream_t stream) {
    const float* positions   = (const float*)d_in[0];
    const float* cell        = (const float*)d_in[1];
    const float* cell_offset = (const float*)d_in[2];
    const float* nmask       = (const float*)d_in[3];
    const float* emb         = (const float*)d_in[4];
    const float* filt_W1     = (const float*)d_in[5];
    const float* filt_b1     = (const float*)d_in[6];
    const float* filt_W2     = (const float*)d_in[7];
    const float* filt_b2     = (const float*)d_in[8];
    const float* in2f_W      = (const float*)d_in[9];
    const float* f2out_W     = (const float*)d_in[10];
    const float* f2out_b     = (const float*)d_in[11];
    const float* dense_W     = (const float*)d_in[12];
    const float* dense_b     = (const float*)d_in[13];
    const int* atomic_numbers = (const int*)d_in[14];
    const int* neighbors      = (const int*)d_in[15];
    float* out = (float*)d_out;

    float* x    = (float*)d_ws;                        // 262144 f32
    float* yb   = x + BB * AA * FF;                    // 262144 f32
    float* agg  = yb + BB * AA * FF;                   // 262144 f32
    float* r_g  = agg + BB * AA * FF;                  // 262144 f32
    float* cm_g = r_g + BB * AA * 128;                 // 262144 f32
    ushort_t* w1t = (ushort_t*)(cm_g + BB * AA * 128); // 12288 u16
    ushort_t* w2f = w1t + 3 * 128 * 32;                // 49152 u16
    ushort_t* whi = w2f + 3 * 16384;                   // 147456 u16
    ushort_t* wlo = whi + 9 * 16384;                   // 147456 u16

    k_setup<<<1024, 256, 0, stream>>>(positions, cell, cell_offset, nmask, neighbors,
                                      filt_W1, filt_W2, in2f_W, f2out_W, dense_W,
                                      emb, atomic_numbers,
                                      r_g, cm_g, w1t, w2f, whi, wlo, x);

    // y0 = x @ in2f_W[0]  (G3-only, permuted write)
    k_ffn<<<256, 512, 0, stream>>>(x, x, x, yb, out,
                                   whi + 3 * 16384, wlo + 3 * 16384, f2out_b,
                                   whi + 6 * 16384, wlo + 6 * 16384, dense_b,
                                   whi + 0 * 16384, wlo + 0 * 16384,
                                   2);
    for (int l = 0; l < 3; ++l) {
        k_cfconv<<<BB * AA / 2, 512, SMEM_BYTES, stream>>>(
            r_g, cm_g, neighbors,
            w1t + (size_t)l * 128 * 32, filt_b1 + (size_t)l * FF,
            w2f + (size_t)l * 16384, filt_b2 + (size_t)l * FF,
            yb, agg);
        int nextl = (l < 2) ? (l + 1) : 0;
        int mode = 1 | ((l < 2) ? 2 : 0) | ((l == 2) ? 4 : 0);
        k_ffn<<<256, 512, 0, stream>>>(agg, x, x, yb, out,
                                       whi + (3 + l) * 16384, wlo + (3 + l) * 16384, f2out_b + (size_t)l * FF,
                                       whi + (6 + l) * 16384, wlo + (6 + l) * 16384, dense_b + (size_t)l * FF,
                                       whi + nextl * 16384, wlo + nextl * 16384,
                                       mode);
    }
}

// Round 15
// 207.316 us; speedup vs baseline: 1.4109x; 1.4109x over previous
//
#include <hip/hip_runtime.h>
#include <math.h>

#define BB 16
#define AA 128
#define NNB 127
#define FF 128
#define GG 25

typedef __attribute__((ext_vector_type(8))) short bf16x8;
typedef __attribute__((ext_vector_type(4))) float f32x4;
typedef unsigned short ushort_t;

#define GLOBAL_LOAD_LDS16(gp, lp)                                                        \
    __builtin_amdgcn_global_load_lds((const __attribute__((address_space(1))) unsigned int*)(gp), \
                                     (__attribute__((address_space(3))) unsigned int*)(lp), 16, 0, 0)

__device__ __forceinline__ float ssp_f(float x) {
    return fmaxf(x, 0.f) + log1pf(__expf(-fabsf(x))) - 0.6931471805599453f;
}

// softplus(x)-ln2 with poly log1p: 1 trans op. |err| <= ~1e-5
__device__ __forceinline__ float ssp_fast(float x) {
    float e = __expf(-fabsf(x));
    float p = fmaf(e, 0.03215845f, -0.13606275f);
    p = fmaf(e, p, 0.28947478f);
    p = fmaf(e, p, -0.49190896f);
    p = fmaf(e, p, 0.99949556f);
    return fmaxf(x, 0.f) + e * p - 0.6931471805599453f;
}

__device__ __forceinline__ ushort_t f2bf(float f) {
    unsigned int u = __float_as_uint(f);
    unsigned int r = (u + 0x7fffu + ((u >> 16) & 1u)) >> 16;
    return (ushort_t)r;
}

__device__ __forceinline__ float bf2f(ushort_t h) {
    return __uint_as_float(((unsigned int)h) << 16);
}

// round-half-up bf16 pair pack: 2 adds + 1 v_perm. err <= 0.5 ulp.
__device__ __forceinline__ unsigned int pack2bf_rhu(float lo, float hi) {
    return __builtin_amdgcn_perm(__float_as_uint(hi) + 0x8000u,
                                 __float_as_uint(lo) + 0x8000u, 0x07060302u);
}

// y column permutation: f and f+16 become adjacent -> float2 epilogue loads
__device__ __forceinline__ int yperm(int f) {
    return (f & ~31) + ((f & 15) << 1) + ((f >> 4) & 1);
}

// ---- fused setup: geometry + weight prep + x init ----
__global__ __launch_bounds__(256) void k_setup(
    const float* __restrict__ positions, const float* __restrict__ cell,
    const float* __restrict__ cell_offset, const float* __restrict__ nmask,
    const int* __restrict__ neighbors,
    const float* __restrict__ W1, const float* __restrict__ W2,
    const float* __restrict__ Win, const float* __restrict__ Wf, const float* __restrict__ Wd,
    const float* __restrict__ emb, const int* __restrict__ z,
    float* __restrict__ r_g, float* __restrict__ cm_g,
    ushort_t* __restrict__ w1t, ushort_t* __restrict__ w2f,
    ushort_t* __restrict__ whi, ushort_t* __restrict__ wlo,
    float* __restrict__ x) {
    int i = blockIdx.x * 256 + threadIdx.x;
    if (i < BB * AA * 128) {
        int row = i >> 7, n = i & 127;
        if (n < NNB) {
            int b = row >> 7;
            int nb = neighbors[row * NNB + n];
            float px = positions[row * 3 + 0], py = positions[row * 3 + 1], pz = positions[row * 3 + 2];
            int nrow = b * AA + nb;
            float qx = positions[nrow * 3 + 0], qy = positions[nrow * 3 + 1], qz = positions[nrow * 3 + 2];
            const float* co = cell_offset + (size_t)row * NNB * 3 + (size_t)n * 3;
            const float* cl = cell + b * 9;
            float c0 = co[0], c1 = co[1], c2 = co[2];
            float ox = c0 * cl[0] + c1 * cl[3] + c2 * cl[6];
            float oy = c0 * cl[1] + c1 * cl[4] + c2 * cl[7];
            float oz = c0 * cl[2] + c1 * cl[5] + c2 * cl[8];
            float dx = qx - px + ox, dy = qy - py + oy, dz = qz - pz + oz;
            float d2 = dx * dx + dy * dy + dz * dz;
            float mk = nmask[row * NNB + n];
            float r = (mk > 0.f) ? sqrtf(d2) : 0.f;
            float Cc = 0.5f * (__cosf(r * (3.14159265358979323846f / 5.0f)) + 1.f);
            Cc = (r < 5.0f) ? Cc : 0.f;
            r_g[i] = r;
            cm_g[i] = Cc * mk;
        } else {
            r_g[i] = 1e9f;   // exp underflows to 0 in phase 1
            cm_g[i] = 0.f;
        }
        int f = i & 127;
        x[i] = emb[z[i >> 7] * FF + f];
    }
    if (i < 3 * 128 * 32) {
        int l = i >> 12, rem = i & 4095, f = rem >> 5, g = rem & 31;
        float v = (g < GG) ? W1[l * GG * FF + g * FF + f] : 0.f;
        w1t[i] = f2bf(v);
    }
    if (i < 3 * 16384) {
        // W2 fragment-ordered: unit u = ((ks*8 + wcft)*64 + lane), 8 bf16 each.
        int l = i >> 14, e = i & 16383;
        int u = e >> 3, j = e & 7;
        int ks = u >> 9, rem = u & 511;
        int wcft = rem >> 6, lane = rem & 63;
        int f = (wcft >> 1) * 32 + (wcft & 1) * 16 + (lane & 15);
        int k = ks * 32 + (lane >> 4) * 8 + j;
        w2f[i] = f2bf(W2[l * 16384 + k * 128 + f]);
    }
    if (i < 9 * 16384) {
        int m = i / 49152;
        int rem = i - m * 49152;
        int l = rem >> 14;
        int rk = rem & 16383;
        int f = rk >> 7, k = rk & 127;
        const float* src = (m == 0) ? Win : ((m == 1) ? Wf : Wd);
        float v = src[l * 16384 + k * 128 + f];
        ushort_t h = f2bf(v);
        whi[i] = h;
        wlo[i] = f2bf(v - bf2f(h));
    }
}

// ---- fused row-GEMM kernel: G1 ts=ssp(agg@Wf+bf); G2 xn=x+ts@Wd+bd; G3 y=xn@Win (permuted) ----
__global__ __launch_bounds__(512) void k_ffn(
    const float* __restrict__ agg, const float* __restrict__ x_in,
    float* __restrict__ x_out, float* __restrict__ y, float* __restrict__ out,
    const ushort_t* __restrict__ wfh, const ushort_t* __restrict__ wfl, const float* __restrict__ bfv_g,
    const ushort_t* __restrict__ wdh, const ushort_t* __restrict__ wdl, const float* __restrict__ bdv_g,
    const ushort_t* __restrict__ wih, const ushort_t* __restrict__ wil,
    int mode) {
    __shared__ ushort_t tsh[8][136];
    __shared__ ushort_t tsl[8][136];
    const int t = threadIdx.x;
    const int lane = t & 63, w = t >> 6;
    const int l15 = lane & 15, l4 = lane >> 4;
    const int r0 = blockIdx.x << 3;
    const int fcol = (w << 4) + l15;

    bf16x8 Ah[4], Al[4];

    auto loadA_global = [&](const float* __restrict__ M) {
#pragma unroll
        for (int ks = 0; ks < 4; ++ks) {
            float v[8];
            if (l15 < 8) {
                const float4* p = (const float4*)(M + ((size_t)(r0 + l15) << 7) + (ks << 5) + (l4 << 3));
                float4 a = p[0], b = p[1];
                v[0] = a.x; v[1] = a.y; v[2] = a.z; v[3] = a.w;
                v[4] = b.x; v[5] = b.y; v[6] = b.z; v[7] = b.w;
            } else {
#pragma unroll
                for (int j = 0; j < 8; ++j) v[j] = 0.f;
            }
#pragma unroll
            for (int j = 0; j < 8; ++j) {
                ushort_t h = f2bf(v[j]);
                Ah[ks][j] = (short)h;
                Al[ks][j] = (short)f2bf(v[j] - bf2f(h));
            }
        }
    };
    auto loadA_lds = [&]() {
#pragma unroll
        for (int ks = 0; ks < 4; ++ks) {
            if (l15 < 8) {
                const char* base = (const char*)&tsh[l15][0] + (ks << 6) + (l4 << 4);
                Ah[ks] = *(const bf16x8*)base;
                const char* basel = (const char*)&tsl[l15][0] + (ks << 6) + (l4 << 4);
                Al[ks] = *(const bf16x8*)basel;
            } else {
#pragma unroll
                for (int j = 0; j < 8; ++j) { Ah[ks][j] = 0; Al[ks][j] = 0; }
            }
        }
    };

    if (mode & 1) {
        loadA_global(agg);
        float bfv = bfv_g[fcol];
        f32x4 acc = {bfv, bfv, bfv, bfv};
#pragma unroll
        for (int ks = 0; ks < 4; ++ks) {
            const bf16x8 Bh = *(const bf16x8*)(wfh + ((size_t)fcol << 7) + (ks << 5) + (l4 << 3));
            const bf16x8 Bl = *(const bf16x8*)(wfl + ((size_t)fcol << 7) + (ks << 5) + (l4 << 3));
            acc = __builtin_amdgcn_mfma_f32_16x16x32_bf16(Al[ks], Bh, acc, 0, 0, 0);
            acc = __builtin_amdgcn_mfma_f32_16x16x32_bf16(Ah[ks], Bl, acc, 0, 0, 0);
            acc = __builtin_amdgcn_mfma_f32_16x16x32_bf16(Ah[ks], Bh, acc, 0, 0, 0);
        }
#pragma unroll
        for (int reg = 0; reg < 4; ++reg) {
            int r = (l4 << 2) + reg;
            if (r < 8) {
                float v = ssp_f(acc[reg]);
                ushort_t h = f2bf(v);
                tsh[r][fcol] = h;
                tsl[r][fcol] = f2bf(v - bf2f(h));
            }
        }
        __syncthreads();
        loadA_lds();
        float bdv = bdv_g[fcol];
        f32x4 acc2 = {bdv, bdv, bdv, bdv};
#pragma unroll
        for (int ks = 0; ks < 4; ++ks) {
            const bf16x8 Bh = *(const bf16x8*)(wdh + ((size_t)fcol << 7) + (ks << 5) + (l4 << 3));
            const bf16x8 Bl = *(const bf16x8*)(wdl + ((size_t)fcol << 7) + (ks << 5) + (l4 << 3));
            acc2 = __builtin_amdgcn_mfma_f32_16x16x32_bf16(Al[ks], Bh, acc2, 0, 0, 0);
            acc2 = __builtin_amdgcn_mfma_f32_16x16x32_bf16(Ah[ks], Bl, acc2, 0, 0, 0);
            acc2 = __builtin_amdgcn_mfma_f32_16x16x32_bf16(Ah[ks], Bh, acc2, 0, 0, 0);
        }
        __syncthreads();
#pragma unroll
        for (int reg = 0; reg < 4; ++reg) {
            int r = (l4 << 2) + reg;
            if (r < 8) {
                size_t gi = ((size_t)(r0 + r) << 7) + fcol;
                float xn = x_in[gi] + acc2[reg];
                x_out[gi] = xn;
                if (mode & 4) out[gi] = xn;
                if (mode & 2) {
                    ushort_t h = f2bf(xn);
                    tsh[r][fcol] = h;
                    tsl[r][fcol] = f2bf(xn - bf2f(h));
                }
            }
        }
        if (mode & 2) __syncthreads();
    }
    if (mode & 2) {
        if (mode & 1) loadA_lds(); else loadA_global(x_in);
        f32x4 acc3 = {0.f, 0.f, 0.f, 0.f};
#pragma unroll
        for (int ks = 0; ks < 4; ++ks) {
            const bf16x8 Bh = *(const bf16x8*)(wih + ((size_t)fcol << 7) + (ks << 5) + (l4 << 3));
            const bf16x8 Bl = *(const bf16x8*)(wil + ((size_t)fcol << 7) + (ks << 5) + (l4 << 3));
            acc3 = __builtin_amdgcn_mfma_f32_16x16x32_bf16(Al[ks], Bh, acc3, 0, 0, 0);
            acc3 = __builtin_amdgcn_mfma_f32_16x16x32_bf16(Ah[ks], Bl, acc3, 0, 0, 0);
            acc3 = __builtin_amdgcn_mfma_f32_16x16x32_bf16(Ah[ks], Bh, acc3, 0, 0, 0);
        }
        const int pf = yperm(fcol);
#pragma unroll
        for (int reg = 0; reg < 4; ++reg) {
            int r = (l4 << 2) + reg;
            if (r < 8) y[((size_t)(r0 + r) << 7) + pf] = acc3[reg];
        }
    }
}

// LDS layout (dynamic, 47104 B), 2 atoms/block:
//  [0,32768)      h bf16 [128n][128f], swizzled: byte = n*256 + ((f*2) ^ ((n&7)<<4))
//  [32768,36864)  red: 8 waves x 128 f32, swizzled (disjoint from h)
//  [36864,45056)  w1t LDS copy (8 KB, linear)
//  [45056,46080)  cm f32[2][128]; [46080,47104) nbr i32[2][128]
#define SMEM_BYTES 47104

__global__ __launch_bounds__(512, 4) void k_cfconv(
    const float* __restrict__ r_g, const float* __restrict__ cm_g,
    const int* __restrict__ neighbors,
    const ushort_t* __restrict__ w1t, const float* __restrict__ b1,
    const ushort_t* __restrict__ w2f, const float* __restrict__ b2,
    const float* __restrict__ y, float* __restrict__ agg) {
    extern __shared__ char smem[];
    float* red_s = (float*)(smem + 32768);
    float* cm_s = (float*)(smem + 45056);
    int* nbr_s = (int*)(smem + 46080);

    const int row0 = blockIdx.x << 1;
    const int b = row0 >> 7;
    const int t = threadIdx.x;
    const int lane = t & 63, w = t >> 6;       // 8 waves
    const int l15 = lane & 15, l4 = lane >> 4;
    const int wr = w >> 2, wc = w & 3;

    // -- async w1t -> LDS (8 KB, one 1-KiB chunk per wave) --
    GLOBAL_LOAD_LDS16((const char*)w1t + (w << 10) + (lane << 4), smem + 36864 + (w << 10));

    // -- W2 fragments into regs ONCE (reused by both atoms); 32 VGPRs --
    bf16x8 w2r[8];
#pragma unroll
    for (int ks = 0; ks < 4; ++ks) {
#pragma unroll
        for (int ft = 0; ft < 2; ++ft)
            w2r[(ks << 1) + ft] = *(const bf16x8*)(w2f + ((((ks << 3) + (wc << 1) + ft) << 6) + lane) * 8);
    }
    const float b2v0 = b2[(wc << 5) + l15];
    const float b2v1 = b2[(wc << 5) + 16 + l15];

    // -- cm/nbr for both atoms --
    if (t < 256) {
        int a = t >> 7, n = t & 127;
        cm_s[(a << 7) + n] = cm_g[((size_t)(row0 + a) << 7) + n];
        nbr_s[(a << 7) + n] = (n < NNB) ? neighbors[(row0 + a) * NNB + n] : 0;
    }
    __syncthreads();   // w1t in LDS (vmcnt drained), cm/nbr visible

#pragma unroll 1
    for (int a = 0; a < 2; ++a) {
        const int row = row0 + a;
        // -- phase 1: fij in regs; D[f][n] = W1T(lds) * fijT; ssp; swizzled h write --
        {
            const int nrow = (w << 4) + l15;
            const float rv = r_g[((size_t)row << 7) + nrow];
            const float width = 5.0f / (GG - 1);
            const float coeff = -0.5f / (width * width);
            float fv[8];
#pragma unroll
            for (int j = 0; j < 8; ++j) {
                int g = (l4 << 3) + j;
                float d = rv - g * width;
                fv[j] = (g < GG) ? __expf(coeff * d * d) : 0.f;   // rv=1e9 pad underflows to 0
            }
            bf16x8 fb;
            unsigned int* fbu = (unsigned int*)&fb;
            fbu[0] = pack2bf_rhu(fv[0], fv[1]);
            fbu[1] = pack2bf_rhu(fv[2], fv[3]);
            fbu[2] = pack2bf_rhu(fv[4], fv[5]);
            fbu[3] = pack2bf_rhu(fv[6], fv[7]);
            const int base = nrow * 256;
            const int sw = (nrow & 7) << 4;
#pragma unroll
            for (int ft = 0; ft < 8; ++ft) {
                bf16x8 aw = *(const bf16x8*)(smem + 36864 + ((((ft << 4) + l15)) << 6) + (l4 << 4));
                const int f0 = (ft << 4) + (l4 << 2);
                f32x4 c0 = *(const f32x4*)(b1 + f0);           // L2 broadcast, per atom
                f32x4 d = __builtin_amdgcn_mfma_f32_16x16x32_bf16(aw, fb, c0, 0, 0, 0);
                unsigned int lo32 = pack2bf_rhu(ssp_fast(d[0]), ssp_fast(d[1]));
                unsigned int hi32 = pack2bf_rhu(ssp_fast(d[2]), ssp_fast(d[3]));
                unsigned long long pk = (unsigned long long)lo32 | ((unsigned long long)hi32 << 32);
                *(unsigned long long*)(smem + base + ((f0 << 1) ^ sw)) = pk;
            }
        }
        __syncthreads();   // h ready

        // -- phase 2: wave (wr,wc) = 64n x 32f; B-frags already in regs --
        f32x4 acc[4][2];
#pragma unroll
        for (int mi = 0; mi < 4; ++mi) {
            f32x4 c00 = {b2v0, b2v0, b2v0, b2v0};
            f32x4 c01 = {b2v1, b2v1, b2v1, b2v1};
            acc[mi][0] = c00;
            acc[mi][1] = c01;
        }
#pragma unroll
        for (int ks = 0; ks < 4; ++ks) {
            bf16x8 ha[4];
#pragma unroll
            for (int mi = 0; mi < 4; ++mi) {
                int n = (wr << 6) + (mi << 4) + l15;
                ha[mi] = *(const bf16x8*)(smem + n * 256 + ((((ks << 2) + l4) << 4) ^ ((n & 7) << 4)));
            }
#pragma unroll
            for (int mi = 0; mi < 4; ++mi) {
                acc[mi][0] = __builtin_amdgcn_mfma_f32_16x16x32_bf16(ha[mi], w2r[(ks << 1)], acc[mi][0], 0, 0, 0);
                acc[mi][1] = __builtin_amdgcn_mfma_f32_16x16x32_bf16(ha[mi], w2r[(ks << 1) + 1], acc[mi][1], 0, 0, 0);
            }
        }
        __syncthreads();   // h reads done (next atom may overwrite h)

        // -- epilogue: permuted-y float2 gathers; vector cm/nbr reads --
        float part0 = 0.f, part1 = 0.f;
        const float* ybase = y + ((size_t)(b * AA) << 7) + (wc << 5) + (l15 << 1);
#pragma unroll
        for (int mi = 0; mi < 4; ++mi) {
            int n0 = (wr << 6) + (mi << 4) + (l4 << 2);
            float4 cmv = *(const float4*)(cm_s + (a << 7) + n0);
            int4 nb4 = *(const int4*)(nbr_s + (a << 7) + n0);
            float2 y0 = *(const float2*)(ybase + ((size_t)nb4.x << 7));
            float2 y1 = *(const float2*)(ybase + ((size_t)nb4.y << 7));
            float2 y2 = *(const float2*)(ybase + ((size_t)nb4.z << 7));
            float2 y3 = *(const float2*)(ybase + ((size_t)nb4.w << 7));
            part0 = fmaf(y0.x, acc[mi][0][0] * cmv.x, part0);
            part1 = fmaf(y0.y, acc[mi][1][0] * cmv.x, part1);
            part0 = fmaf(y1.x, acc[mi][0][1] * cmv.y, part0);
            part1 = fmaf(y1.y, acc[mi][1][1] * cmv.y, part1);
            part0 = fmaf(y2.x, acc[mi][0][2] * cmv.z, part0);
            part1 = fmaf(y2.y, acc[mi][1][2] * cmv.z, part1);
            part0 = fmaf(y3.x, acc[mi][0][3] * cmv.w, part0);
            part1 = fmaf(y3.y, acc[mi][1][3] * cmv.w, part1);
        }
        {
            int xg = l4 << 3;
            red_s[(w << 7) + (l4 << 5) + (l15 ^ xg)] = part0;
            red_s[(w << 7) + (l4 << 5) + ((16 + l15) ^ xg)] = part1;
        }
        __syncthreads();   // red ready
        if (t < FF) {
            int wcf = t >> 5, fl = t & 31;
            float s = 0.f;
#pragma unroll
            for (int wr2 = 0; wr2 < 2; ++wr2)
#pragma unroll
                for (int g = 0; g < 4; ++g)
                    s += red_s[(((wr2 << 2) + wcf) << 7) + (g << 5) + (fl ^ (g << 3))];
            agg[(size_t)row * FF + t] = s;
        }
        // next atom's phase-1 h writes don't touch red_s (disjoint); h reads synced above
    }
}

extern "C" void kernel_launch(void* const* d_in, const int* in_sizes, int n_in,
                              void* d_out, int out_size, void* d_ws, size_t ws_size,
                              hipStream_t stream) {
    const float* positions   = (const float*)d_in[0];
    const float* cell        = (const float*)d_in[1];
    const float* cell_offset = (const float*)d_in[2];
    const float* nmask       = (const float*)d_in[3];
    const float* emb         = (const float*)d_in[4];
    const float* filt_W1     = (const float*)d_in[5];
    const float* filt_b1     = (const float*)d_in[6];
    const float* filt_W2     = (const float*)d_in[7];
    const float* filt_b2     = (const float*)d_in[8];
    const float* in2f_W      = (const float*)d_in[9];
    const float* f2out_W     = (const float*)d_in[10];
    const float* f2out_b     = (const float*)d_in[11];
    const float* dense_W     = (const float*)d_in[12];
    const float* dense_b     = (const float*)d_in[13];
    const int* atomic_numbers = (const int*)d_in[14];
    const int* neighbors      = (const int*)d_in[15];
    float* out = (float*)d_out;

    float* x    = (float*)d_ws;                        // 262144 f32
    float* yb   = x + BB * AA * FF;                    // 262144 f32
    float* agg  = yb + BB * AA * FF;                   // 262144 f32
    float* r_g  = agg + BB * AA * FF;                  // 262144 f32
    float* cm_g = r_g + BB * AA * 128;                 // 262144 f32
    ushort_t* w1t = (ushort_t*)(cm_g + BB * AA * 128); // 12288 u16
    ushort_t* w2f = w1t + 3 * 128 * 32;                // 49152 u16
    ushort_t* whi = w2f + 3 * 16384;                   // 147456 u16
    ushort_t* wlo = whi + 9 * 16384;                   // 147456 u16

    k_setup<<<1024, 256, 0, stream>>>(positions, cell, cell_offset, nmask, neighbors,
                                      filt_W1, filt_W2, in2f_W, f2out_W, dense_W,
                                      emb, atomic_numbers,
                                      r_g, cm_g, w1t, w2f, whi, wlo, x);

    // y0 = x @ in2f_W[0]  (G3-only, permuted write)
    k_ffn<<<256, 512, 0, stream>>>(x, x, x, yb, out,
                                   whi + 3 * 16384, wlo + 3 * 16384, f2out_b,
                                   whi + 6 * 16384, wlo + 6 * 16384, dense_b,
                                   whi + 0 * 16384, wlo + 0 * 16384,
                                   2);
    for (int l = 0; l < 3; ++l) {
        k_cfconv<<<BB * AA / 2, 512, SMEM_BYTES, stream>>>(
            r_g, cm_g, neighbors,
            w1t + (size_t)l * 128 * 32, filt_b1 + (size_t)l * FF,
            w2f + (size_t)l * 16384, filt_b2 + (size_t)l * FF,
            yb, agg);
        int nextl = (l < 2) ? (l + 1) : 0;
        int mode = 1 | ((l < 2) ? 2 : 0) | ((l == 2) ? 4 : 0);
        k_ffn<<<256, 512, 0, stream>>>(agg, x, x, yb, out,
                                       whi + (3 + l) * 16384, wlo + (3 + l) * 16384, f2out_b + (size_t)l * FF,
                                       whi + (6 + l) * 16384, wlo + (6 + l) * 16384, dense_b + (size_t)l * FF,
                                       whi + nextl * 16384, wlo + nextl * 16384,
                                       mode);
    }
}

// Round 16
// 133.410 us; speedup vs baseline: 2.1925x; 1.5540x over previous
//
#include <hip/hip_runtime.h>
#include <math.h>

#define BB 16
#define AA 128
#define NNB 127
#define FF 128
#define GG 25

typedef __attribute__((ext_vector_type(8))) short bf16x8;
typedef __attribute__((ext_vector_type(4))) float f32x4;
typedef unsigned short ushort_t;

__device__ __forceinline__ float ssp_f(float x) {
    return fmaxf(x, 0.f) + log1pf(__expf(-fabsf(x))) - 0.6931471805599453f;
}

// softplus(x)-ln2 with poly log1p: 1 trans op. |err| <= ~1e-5
__device__ __forceinline__ float ssp_fast(float x) {
    float e = __expf(-fabsf(x));
    float p = fmaf(e, 0.03215845f, -0.13606275f);
    p = fmaf(e, p, 0.28947478f);
    p = fmaf(e, p, -0.49190896f);
    p = fmaf(e, p, 0.99949556f);
    return fmaxf(x, 0.f) + e * p - 0.6931471805599453f;
}

__device__ __forceinline__ ushort_t f2bf(float f) {
    unsigned int u = __float_as_uint(f);
    unsigned int r = (u + 0x7fffu + ((u >> 16) & 1u)) >> 16;
    return (ushort_t)r;
}

__device__ __forceinline__ float bf2f(ushort_t h) {
    return __uint_as_float(((unsigned int)h) << 16);
}

// round-half-up bf16 pair pack: 2 adds + 1 v_perm. err <= 0.5 ulp.
__device__ __forceinline__ unsigned int pack2bf_rhu(float lo, float hi) {
    return __builtin_amdgcn_perm(__float_as_uint(hi) + 0x8000u,
                                 __float_as_uint(lo) + 0x8000u, 0x07060302u);
}

// ---- fused setup: geometry + weight prep + x init ----
__global__ __launch_bounds__(256) void k_setup(
    const float* __restrict__ positions, const float* __restrict__ cell,
    const float* __restrict__ cell_offset, const float* __restrict__ nmask,
    const int* __restrict__ neighbors,
    const float* __restrict__ W1, const float* __restrict__ W2,
    const float* __restrict__ Win, const float* __restrict__ Wf, const float* __restrict__ Wd,
    const float* __restrict__ emb, const int* __restrict__ z,
    float* __restrict__ r_g, float* __restrict__ cm_g,
    ushort_t* __restrict__ w1t, ushort_t* __restrict__ w2f,
    ushort_t* __restrict__ whi, ushort_t* __restrict__ wlo,
    float* __restrict__ x) {
    int i = blockIdx.x * 256 + threadIdx.x;
    if (i < BB * AA * 128) {
        int row = i >> 7, n = i & 127;
        if (n < NNB) {
            int b = row >> 7;
            int nb = neighbors[row * NNB + n];
            float px = positions[row * 3 + 0], py = positions[row * 3 + 1], pz = positions[row * 3 + 2];
            int nrow = b * AA + nb;
            float qx = positions[nrow * 3 + 0], qy = positions[nrow * 3 + 1], qz = positions[nrow * 3 + 2];
            const float* co = cell_offset + (size_t)row * NNB * 3 + (size_t)n * 3;
            const float* cl = cell + b * 9;
            float c0 = co[0], c1 = co[1], c2 = co[2];
            float ox = c0 * cl[0] + c1 * cl[3] + c2 * cl[6];
            float oy = c0 * cl[1] + c1 * cl[4] + c2 * cl[7];
            float oz = c0 * cl[2] + c1 * cl[5] + c2 * cl[8];
            float dx = qx - px + ox, dy = qy - py + oy, dz = qz - pz + oz;
            float d2 = dx * dx + dy * dy + dz * dz;
            float mk = nmask[row * NNB + n];
            float r = (mk > 0.f) ? sqrtf(d2) : 0.f;
            float Cc = 0.5f * (__cosf(r * (3.14159265358979323846f / 5.0f)) + 1.f);
            Cc = (r < 5.0f) ? Cc : 0.f;
            r_g[i] = r;
            cm_g[i] = Cc * mk;
        } else {
            r_g[i] = 1e9f;   // exp underflows to 0 in phase 1
            cm_g[i] = 0.f;
        }
        int f = i & 127;
        x[i] = emb[z[i >> 7] * FF + f];
    }
    if (i < 3 * 128 * 32) {
        int l = i >> 12, rem = i & 4095, f = rem >> 5, g = rem & 31;
        float v = (g < GG) ? W1[l * GG * FF + g * FF + f] : 0.f;
        w1t[i] = f2bf(v);
    }
    if (i < 3 * 16384) {
        // W2 fragment-ordered: unit u = ((ks*8 + ftile)*64 + lane), 8 bf16 each.
        int l = i >> 14, e = i & 16383;
        int u = e >> 3, j = e & 7;
        int ks = u >> 9, rem = u & 511;
        int wcft = rem >> 6, lane = rem & 63;
        int f = (wcft >> 1) * 32 + (wcft & 1) * 16 + (lane & 15);   // == wcft*16 + (lane&15)
        int k = ks * 32 + (lane >> 4) * 8 + j;
        w2f[i] = f2bf(W2[l * 16384 + k * 128 + f]);
    }
    if (i < 9 * 16384) {
        int m = i / 49152;
        int rem = i - m * 49152;
        int l = rem >> 14;
        int rk = rem & 16383;
        int f = rk >> 7, k = rk & 127;
        const float* src = (m == 0) ? Win : ((m == 1) ? Wf : Wd);
        float v = src[l * 16384 + k * 128 + f];
        ushort_t h = f2bf(v);
        whi[i] = h;
        wlo[i] = f2bf(v - bf2f(h));
    }
}

// ---- fused row-GEMM kernel: G1 ts=ssp((agg0+agg1)@Wf+bf); G2 xn=x+ts@Wd+bd; G3 y=xn@Win ----
__global__ __launch_bounds__(512) void k_ffn(
    const float* __restrict__ agg0, const float* __restrict__ agg1,
    const float* __restrict__ x_in,
    float* __restrict__ x_out, float* __restrict__ y, float* __restrict__ out,
    const ushort_t* __restrict__ wfh, const ushort_t* __restrict__ wfl, const float* __restrict__ bfv_g,
    const ushort_t* __restrict__ wdh, const ushort_t* __restrict__ wdl, const float* __restrict__ bdv_g,
    const ushort_t* __restrict__ wih, const ushort_t* __restrict__ wil,
    int mode) {
    __shared__ ushort_t tsh[8][136];
    __shared__ ushort_t tsl[8][136];
    const int t = threadIdx.x;
    const int lane = t & 63, w = t >> 6;
    const int l15 = lane & 15, l4 = lane >> 4;
    const int r0 = blockIdx.x << 3;
    const int fcol = (w << 4) + l15;

    bf16x8 Ah[4], Al[4];

    auto splitA = [&](float* v) {
#pragma unroll
        for (int ks = 0; ks < 4; ++ks)
#pragma unroll
            for (int j = 0; j < 8; ++j) {
                float vv = v[ks * 8 + j];
                ushort_t h = f2bf(vv);
                Ah[ks][j] = (short)h;
                Al[ks][j] = (short)f2bf(vv - bf2f(h));
            }
    };
    auto loadA_global = [&](const float* __restrict__ M) {
        float v[32];
#pragma unroll
        for (int ks = 0; ks < 4; ++ks) {
            if (l15 < 8) {
                const float4* p = (const float4*)(M + ((size_t)(r0 + l15) << 7) + (ks << 5) + (l4 << 3));
                float4 a = p[0], c = p[1];
                v[ks * 8 + 0] = a.x; v[ks * 8 + 1] = a.y; v[ks * 8 + 2] = a.z; v[ks * 8 + 3] = a.w;
                v[ks * 8 + 4] = c.x; v[ks * 8 + 5] = c.y; v[ks * 8 + 6] = c.z; v[ks * 8 + 7] = c.w;
            } else {
#pragma unroll
                for (int j = 0; j < 8; ++j) v[ks * 8 + j] = 0.f;
            }
        }
        splitA(v);
    };
    auto loadA_sum = [&](const float* __restrict__ M, const float* __restrict__ M2) {
        float v[32];
#pragma unroll
        for (int ks = 0; ks < 4; ++ks) {
            if (l15 < 8) {
                size_t off = ((size_t)(r0 + l15) << 7) + (ks << 5) + (l4 << 3);
                const float4* p = (const float4*)(M + off);
                const float4* q = (const float4*)(M2 + off);
                float4 a = p[0], c = p[1], a2 = q[0], c2 = q[1];
                v[ks * 8 + 0] = a.x + a2.x; v[ks * 8 + 1] = a.y + a2.y;
                v[ks * 8 + 2] = a.z + a2.z; v[ks * 8 + 3] = a.w + a2.w;
                v[ks * 8 + 4] = c.x + c2.x; v[ks * 8 + 5] = c.y + c2.y;
                v[ks * 8 + 6] = c.z + c2.z; v[ks * 8 + 7] = c.w + c2.w;
            } else {
#pragma unroll
                for (int j = 0; j < 8; ++j) v[ks * 8 + j] = 0.f;
            }
        }
        splitA(v);
    };
    auto loadA_lds = [&]() {
#pragma unroll
        for (int ks = 0; ks < 4; ++ks) {
            if (l15 < 8) {
                Ah[ks] = *(const bf16x8*)((const char*)&tsh[l15][0] + (ks << 6) + (l4 << 4));
                Al[ks] = *(const bf16x8*)((const char*)&tsl[l15][0] + (ks << 6) + (l4 << 4));
            } else {
#pragma unroll
                for (int j = 0; j < 8; ++j) { Ah[ks][j] = 0; Al[ks][j] = 0; }
            }
        }
    };

    if (mode & 1) {
        loadA_sum(agg0, agg1);
        float bfv = bfv_g[fcol];
        f32x4 acc = {bfv, bfv, bfv, bfv};
#pragma unroll
        for (int ks = 0; ks < 4; ++ks) {
            const bf16x8 Bh = *(const bf16x8*)(wfh + ((size_t)fcol << 7) + (ks << 5) + (l4 << 3));
            const bf16x8 Bl = *(const bf16x8*)(wfl + ((size_t)fcol << 7) + (ks << 5) + (l4 << 3));
            acc = __builtin_amdgcn_mfma_f32_16x16x32_bf16(Al[ks], Bh, acc, 0, 0, 0);
            acc = __builtin_amdgcn_mfma_f32_16x16x32_bf16(Ah[ks], Bl, acc, 0, 0, 0);
            acc = __builtin_amdgcn_mfma_f32_16x16x32_bf16(Ah[ks], Bh, acc, 0, 0, 0);
        }
#pragma unroll
        for (int reg = 0; reg < 4; ++reg) {
            int r = (l4 << 2) + reg;
            if (r < 8) {
                float v = ssp_f(acc[reg]);
                ushort_t h = f2bf(v);
                tsh[r][fcol] = h;
                tsl[r][fcol] = f2bf(v - bf2f(h));
            }
        }
        __syncthreads();
        loadA_lds();
        float bdv = bdv_g[fcol];
        f32x4 acc2 = {bdv, bdv, bdv, bdv};
#pragma unroll
        for (int ks = 0; ks < 4; ++ks) {
            const bf16x8 Bh = *(const bf16x8*)(wdh + ((size_t)fcol << 7) + (ks << 5) + (l4 << 3));
            const bf16x8 Bl = *(const bf16x8*)(wdl + ((size_t)fcol << 7) + (ks << 5) + (l4 << 3));
            acc2 = __builtin_amdgcn_mfma_f32_16x16x32_bf16(Al[ks], Bh, acc2, 0, 0, 0);
            acc2 = __builtin_amdgcn_mfma_f32_16x16x32_bf16(Ah[ks], Bl, acc2, 0, 0, 0);
            acc2 = __builtin_amdgcn_mfma_f32_16x16x32_bf16(Ah[ks], Bh, acc2, 0, 0, 0);
        }
        __syncthreads();
#pragma unroll
        for (int reg = 0; reg < 4; ++reg) {
            int r = (l4 << 2) + reg;
            if (r < 8) {
                size_t gi = ((size_t)(r0 + r) << 7) + fcol;
                float xn = x_in[gi] + acc2[reg];
                x_out[gi] = xn;
                if (mode & 4) out[gi] = xn;
                if (mode & 2) {
                    ushort_t h = f2bf(xn);
                    tsh[r][fcol] = h;
                    tsl[r][fcol] = f2bf(xn - bf2f(h));
                }
            }
        }
        if (mode & 2) __syncthreads();
    }
    if (mode & 2) {
        if (mode & 1) loadA_lds(); else loadA_global(x_in);
        f32x4 acc3 = {0.f, 0.f, 0.f, 0.f};
#pragma unroll
        for (int ks = 0; ks < 4; ++ks) {
            const bf16x8 Bh = *(const bf16x8*)(wih + ((size_t)fcol << 7) + (ks << 5) + (l4 << 3));
            const bf16x8 Bl = *(const bf16x8*)(wil + ((size_t)fcol << 7) + (ks << 5) + (l4 << 3));
            acc3 = __builtin_amdgcn_mfma_f32_16x16x32_bf16(Al[ks], Bh, acc3, 0, 0, 0);
            acc3 = __builtin_amdgcn_mfma_f32_16x16x32_bf16(Ah[ks], Bl, acc3, 0, 0, 0);
            acc3 = __builtin_amdgcn_mfma_f32_16x16x32_bf16(Ah[ks], Bh, acc3, 0, 0, 0);
        }
#pragma unroll
        for (int reg = 0; reg < 4; ++reg) {
            int r = (l4 << 2) + reg;
            if (r < 8) y[((size_t)(r0 + r) << 7) + fcol] = acc3[reg];
        }
    }
}

// LDS layout (22016 B), half-atom blocks (64 neighbors):
//  [0,16384)      h bf16 [64n][128f], swizzled: byte = n*256 + ((f*2) ^ ((n&7)<<4))
//  [16384,21504)  fij bf16 [64n][40] (80 B rows: 32 g + 8 pad for bank spread)
//  [21504,21760)  cm f32[64]; [21760,22016) nbr i32[64]
#define SMEM_BYTES 22016

__global__ __launch_bounds__(512, 4) void k_cfconv(
    const float* __restrict__ r_g, const float* __restrict__ cm_g,
    const int* __restrict__ neighbors,
    const ushort_t* __restrict__ w1t, const float* __restrict__ b1,
    const ushort_t* __restrict__ w2f, const float* __restrict__ b2,
    const float* __restrict__ y,
    float* __restrict__ agg0, float* __restrict__ agg1) {
    extern __shared__ char smem[];
    float* cm_s = (float*)(smem + 21504);
    int* nbr_s = (int*)(smem + 21760);

    const int bid = blockIdx.x;
    const int row = bid >> 1;        // atom
    const int hh = bid & 1;          // neighbor half
    const int b = row >> 7;
    const int t = threadIdx.x;
    const int lane = t & 63, w = t >> 6;   // 8 waves; wave w owns f-tile [w*16, w*16+16)
    const int l15 = lane & 15, l4 = lane >> 4;

    // -- prefetch (L2): W2 frags for f-tile w (4 x 16B), W1T A-frag, b1, b2 --
    bf16x8 w2r[4];
#pragma unroll
    for (int ks = 0; ks < 4; ++ks)
        w2r[ks] = *(const bf16x8*)(w2f + ((((ks << 3) + w) << 6) + lane) * 8);
    const bf16x8 aw = *(const bf16x8*)(w1t + ((w << 4) + l15) * 32 + (l4 << 3));
    const f32x4 b1v = *(const f32x4*)(b1 + (w << 4) + (l4 << 2));
    const float b2v = b2[(w << 4) + l15];

    // -- stage cm/nbr for this half --
    if (t < 64) {
        int ng = (hh << 6) + t;
        cm_s[t] = cm_g[((size_t)row << 7) + ng];
        nbr_s[t] = (ng < NNB) ? neighbors[row * NNB + ng] : 0;
    }
    // -- fij: 4 gaussians per thread -> LDS [64][40] bf16 (80 B rows) --
    {
        int nl = t >> 3, g0 = (t & 7) << 2;
        float rv = r_g[((size_t)row << 7) + (hh << 6) + nl];
        const float width = 5.0f / (GG - 1);
        const float coeff = -0.5f / (width * width);
        float v[4];
#pragma unroll
        for (int j = 0; j < 4; ++j) {
            int g = g0 + j;
            float d = rv - g * width;
            v[j] = (g < GG) ? __expf(coeff * d * d) : 0.f;   // rv=1e9 pad underflows to 0
        }
        unsigned long long pk = (unsigned long long)pack2bf_rhu(v[0], v[1])
            | ((unsigned long long)pack2bf_rhu(v[2], v[3]) << 32);
        *(unsigned long long*)(smem + 16384 + nl * 80 + (g0 << 1)) = pk;
    }
    __syncthreads();   // (A) fij + cm/nbr ready

    // -- phase 1: 4 MFMA; D[f][n] = W1T * fijT; ssp; swizzled h write --
    {
        bf16x8 fb[4];
#pragma unroll
        for (int ng = 0; ng < 4; ++ng)
            fb[ng] = *(const bf16x8*)(smem + 16384 + ((ng << 4) + l15) * 80 + (l4 << 4));
        const int f0 = (w << 4) + (l4 << 2);
#pragma unroll
        for (int ng = 0; ng < 4; ++ng) {
            f32x4 d = __builtin_amdgcn_mfma_f32_16x16x32_bf16(aw, fb[ng], b1v, 0, 0, 0);
            int nl = (ng << 4) + l15;
            unsigned int lo32 = pack2bf_rhu(ssp_fast(d[0]), ssp_fast(d[1]));
            unsigned int hi32 = pack2bf_rhu(ssp_fast(d[2]), ssp_fast(d[3]));
            unsigned long long pk = (unsigned long long)lo32 | ((unsigned long long)hi32 << 32);
            *(unsigned long long*)(smem + nl * 256 + ((f0 << 1) ^ ((nl & 7) << 4))) = pk;
        }
    }
    __syncthreads();   // (B) h ready

    // -- phase 2: 16 MFMA; wave = 64n x 16f, W2 frags in regs --
    f32x4 acc[4];
#pragma unroll
    for (int mi = 0; mi < 4; ++mi) {
        f32x4 c = {b2v, b2v, b2v, b2v};
        acc[mi] = c;
    }
#pragma unroll
    for (int ks = 0; ks < 4; ++ks) {
#pragma unroll
        for (int mi = 0; mi < 4; ++mi) {
            int nl = (mi << 4) + l15;
            bf16x8 ha = *(const bf16x8*)(smem + nl * 256 + ((((ks << 2) + l4) << 4) ^ ((nl & 7) << 4)));
            acc[mi] = __builtin_amdgcn_mfma_f32_16x16x32_bf16(ha, w2r[ks], acc[mi], 0, 0, 0);
        }
    }

    // -- epilogue: f fixed per lane; 16 y-gathers; shfl reduce over l4 groups --
    float part = 0.f;
    const int f = (w << 4) + l15;
    const float* yb2 = y + ((size_t)(b * AA) << 7) + f;
#pragma unroll
    for (int mi = 0; mi < 4; ++mi) {
        int n0 = (mi << 4) + (l4 << 2);
        float4 cmv = *(const float4*)(cm_s + n0);
        int4 nb4 = *(const int4*)(nbr_s + n0);
        part = fmaf(yb2[(size_t)nb4.x << 7], acc[mi][0] * cmv.x, part);
        part = fmaf(yb2[(size_t)nb4.y << 7], acc[mi][1] * cmv.y, part);
        part = fmaf(yb2[(size_t)nb4.z << 7], acc[mi][2] * cmv.z, part);
        part = fmaf(yb2[(size_t)nb4.w << 7], acc[mi][3] * cmv.w, part);
    }
    part += __shfl_xor(part, 16);
    part += __shfl_xor(part, 32);
    if (l4 == 0) {
        float* aggp = hh ? agg1 : agg0;
        aggp[((size_t)row << 7) + f] = part;
    }
}

extern "C" void kernel_launch(void* const* d_in, const int* in_sizes, int n_in,
                              void* d_out, int out_size, void* d_ws, size_t ws_size,
                              hipStream_t stream) {
    const float* positions   = (const float*)d_in[0];
    const float* cell        = (const float*)d_in[1];
    const float* cell_offset = (const float*)d_in[2];
    const float* nmask       = (const float*)d_in[3];
    const float* emb         = (const float*)d_in[4];
    const float* filt_W1     = (const float*)d_in[5];
    const float* filt_b1     = (const float*)d_in[6];
    const float* filt_W2     = (const float*)d_in[7];
    const float* filt_b2     = (const float*)d_in[8];
    const float* in2f_W      = (const float*)d_in[9];
    const float* f2out_W     = (const float*)d_in[10];
    const float* f2out_b     = (const float*)d_in[11];
    const float* dense_W     = (const float*)d_in[12];
    const float* dense_b     = (const float*)d_in[13];
    const int* atomic_numbers = (const int*)d_in[14];
    const int* neighbors      = (const int*)d_in[15];
    float* out = (float*)d_out;

    float* x    = (float*)d_ws;                        // 262144 f32
    float* yb   = x + BB * AA * FF;                    // 262144 f32
    float* agg0 = yb + BB * AA * FF;                   // 262144 f32
    float* agg1 = agg0 + BB * AA * FF;                 // 262144 f32
    float* r_g  = agg1 + BB * AA * FF;                 // 262144 f32
    float* cm_g = r_g + BB * AA * 128;                 // 262144 f32
    ushort_t* w1t = (ushort_t*)(cm_g + BB * AA * 128); // 12288 u16
    ushort_t* w2f = w1t + 3 * 128 * 32;                // 49152 u16
    ushort_t* whi = w2f + 3 * 16384;                   // 147456 u16
    ushort_t* wlo = whi + 9 * 16384;                   // 147456 u16

    k_setup<<<1024, 256, 0, stream>>>(positions, cell, cell_offset, nmask, neighbors,
                                      filt_W1, filt_W2, in2f_W, f2out_W, dense_W,
                                      emb, atomic_numbers,
                                      r_g, cm_g, w1t, w2f, whi, wlo, x);

    // y0 = x @ in2f_W[0]  (G3-only)
    k_ffn<<<256, 512, 0, stream>>>(x, x, x, x, yb, out,
                                   whi + 3 * 16384, wlo + 3 * 16384, f2out_b,
                                   whi + 6 * 16384, wlo + 6 * 16384, dense_b,
                                   whi + 0 * 16384, wlo + 0 * 16384,
                                   2);
    for (int l = 0; l < 3; ++l) {
        k_cfconv<<<BB * AA * 2, 512, SMEM_BYTES, stream>>>(
            r_g, cm_g, neighbors,
            w1t + (size_t)l * 128 * 32, filt_b1 + (size_t)l * FF,
            w2f + (size_t)l * 16384, filt_b2 + (size_t)l * FF,
            yb, agg0, agg1);
        int nextl = (l < 2) ? (l + 1) : 0;
        int mode = 1 | ((l < 2) ? 2 : 0) | ((l == 2) ? 4 : 0);
        k_ffn<<<256, 512, 0, stream>>>(agg0, agg1, x, x, yb, out,
                                       whi + (3 + l) * 16384, wlo + (3 + l) * 16384, f2out_b + (size_t)l * FF,
                                       whi + (6 + l) * 16384, wlo + (6 + l) * 16384, dense_b + (size_t)l * FF,
                                       whi + nextl * 16384, wlo + nextl * 16384,
                                       mode);
    }
}

// Round 17
// 126.455 us; speedup vs baseline: 2.3131x; 1.0550x over previous
//
#include <hip/hip_runtime.h>
#include <math.h>

#define BB 16
#define AA 128
#define NNB 127
#define FF 128
#define GG 25

typedef __attribute__((ext_vector_type(8))) short bf16x8;
typedef __attribute__((ext_vector_type(4))) float f32x4;
typedef unsigned short ushort_t;

__device__ __forceinline__ float ssp_f(float x) {
    return fmaxf(x, 0.f) + log1pf(__expf(-fabsf(x))) - 0.6931471805599453f;
}

// softplus(x)-ln2 with poly log1p: 1 trans op. |err| <= ~1e-5
__device__ __forceinline__ float ssp_fast(float x) {
    float e = __expf(-fabsf(x));
    float p = fmaf(e, 0.03215845f, -0.13606275f);
    p = fmaf(e, p, 0.28947478f);
    p = fmaf(e, p, -0.49190896f);
    p = fmaf(e, p, 0.99949556f);
    return fmaxf(x, 0.f) + e * p - 0.6931471805599453f;
}

__device__ __forceinline__ ushort_t f2bf(float f) {
    unsigned int u = __float_as_uint(f);
    unsigned int r = (u + 0x7fffu + ((u >> 16) & 1u)) >> 16;
    return (ushort_t)r;
}

__device__ __forceinline__ float bf2f(ushort_t h) {
    return __uint_as_float(((unsigned int)h) << 16);
}

// round-half-up bf16 pair pack: 2 adds + 1 v_perm (vs ~10 ops RNE). err <= 0.5 ulp.
__device__ __forceinline__ unsigned int pack2bf_rhu(float lo, float hi) {
    return __builtin_amdgcn_perm(__float_as_uint(hi) + 0x8000u,
                                 __float_as_uint(lo) + 0x8000u, 0x07060302u);
}

// ---- geometry precompute (once for all 3 layers): r, cm = cutoff*mask ----
__global__ __launch_bounds__(256) void k_geom(const float* __restrict__ positions,
                                              const float* __restrict__ cell,
                                              const float* __restrict__ cell_offset,
                                              const float* __restrict__ nmask,
                                              const int* __restrict__ neighbors,
                                              float* __restrict__ r_g,
                                              float* __restrict__ cm_g) {
    int i = blockIdx.x * 256 + threadIdx.x;   // over 2048*128
    if (i >= BB * AA * 128) return;
    int row = i >> 7, n = i & 127;
    if (n < NNB) {
        int b = row >> 7;
        int nb = neighbors[row * NNB + n];
        float px = positions[row * 3 + 0], py = positions[row * 3 + 1], pz = positions[row * 3 + 2];
        int nrow = b * AA + nb;
        float qx = positions[nrow * 3 + 0], qy = positions[nrow * 3 + 1], qz = positions[nrow * 3 + 2];
        const float* co = cell_offset + (size_t)row * NNB * 3 + (size_t)n * 3;
        const float* cl = cell + b * 9;
        float c0 = co[0], c1 = co[1], c2 = co[2];
        float ox = c0 * cl[0] + c1 * cl[3] + c2 * cl[6];
        float oy = c0 * cl[1] + c1 * cl[4] + c2 * cl[7];
        float oz = c0 * cl[2] + c1 * cl[5] + c2 * cl[8];
        float dx = qx - px + ox, dy = qy - py + oy, dz = qz - pz + oz;
        float d2 = dx * dx + dy * dy + dz * dz;
        float mk = nmask[row * NNB + n];
        float r = (mk > 0.f) ? sqrtf(d2) : 0.f;
        float Cc = 0.5f * (__cosf(r * (3.14159265358979323846f / 5.0f)) + 1.f);
        Cc = (r < 5.0f) ? Cc : 0.f;
        r_g[i] = r;
        cm_g[i] = Cc * mk;
    } else {
        r_g[i] = 1e9f;
        cm_g[i] = 0.f;
    }
}

// ---- prep: W1T bf16; W2 fragment-ordered bf16; ffn weights hi/lo split bf16 [f][k] ----
__global__ __launch_bounds__(256) void k_prep(const float* __restrict__ W1,
                                              const float* __restrict__ W2,
                                              const float* __restrict__ Win,
                                              const float* __restrict__ Wf,
                                              const float* __restrict__ Wd,
                                              ushort_t* __restrict__ w1t,
                                              ushort_t* __restrict__ w2f,
                                              ushort_t* __restrict__ whi,
                                              ushort_t* __restrict__ wlo) {
    int i = blockIdx.x * 256 + threadIdx.x;
    if (i < 3 * 128 * 32) {
        int l = i >> 12, rem = i & 4095, f = rem >> 5, g = rem & 31;
        float v = (g < GG) ? W1[l * GG * FF + g * FF + f] : 0.f;
        w1t[i] = f2bf(v);
    }
    if (i < 3 * 16384) {
        // fragment-ordered: unit u = ((ks*8 + wcft)*64 + lane), 8 bf16 each.
        int l = i >> 14, e = i & 16383;
        int u = e >> 3, j = e & 7;
        int ks = u >> 9, rem = u & 511;
        int wcft = rem >> 6, lane = rem & 63;
        int f = (wcft >> 1) * 32 + (wcft & 1) * 16 + (lane & 15);
        int k = ks * 32 + (lane >> 4) * 8 + j;
        w2f[i] = f2bf(W2[l * 16384 + k * 128 + f]);
    }
    if (i < 9 * 16384) {
        int m = i / 49152;
        int rem = i - m * 49152;
        int l = rem >> 14;
        int rk = rem & 16383;
        int f = rk >> 7, k = rk & 127;
        const float* src = (m == 0) ? Win : ((m == 1) ? Wf : Wd);
        float v = src[l * 16384 + k * 128 + f];
        ushort_t h = f2bf(v);
        whi[i] = h;
        wlo[i] = f2bf(v - bf2f(h));
    }
}

// ---- x init ----
__global__ __launch_bounds__(256) void k_init_x(const float* __restrict__ emb,
                                                const int* __restrict__ z,
                                                float* __restrict__ x) {
    int i = blockIdx.x * 256 + threadIdx.x;
    if (i < BB * AA * FF) {
        int row = i >> 7, f = i & 127;
        x[i] = emb[z[row] * FF + f];
    }
}

// ---- fused row-GEMM kernel: G1 ts=ssp(agg@Wf+bf); G2 xn=x+ts@Wd+bd; G3 y=xn@Win ----
__global__ __launch_bounds__(512) void k_ffn(
    const float* __restrict__ agg, const float* __restrict__ x_in,
    float* __restrict__ x_out, float* __restrict__ y, float* __restrict__ out,
    const ushort_t* __restrict__ wfh, const ushort_t* __restrict__ wfl, const float* __restrict__ bfv_g,
    const ushort_t* __restrict__ wdh, const ushort_t* __restrict__ wdl, const float* __restrict__ bdv_g,
    const ushort_t* __restrict__ wih, const ushort_t* __restrict__ wil,
    int mode) {
    __shared__ ushort_t tsh[8][136];
    __shared__ ushort_t tsl[8][136];
    const int t = threadIdx.x;
    const int lane = t & 63, w = t >> 6;
    const int l15 = lane & 15, l4 = lane >> 4;
    const int r0 = blockIdx.x << 3;
    const int fcol = (w << 4) + l15;

    bf16x8 Ah[4], Al[4];

    auto loadA_global = [&](const float* __restrict__ M) {
#pragma unroll
        for (int ks = 0; ks < 4; ++ks) {
            float v[8];
            if (l15 < 8) {
                const float4* p = (const float4*)(M + ((size_t)(r0 + l15) << 7) + (ks << 5) + (l4 << 3));
                float4 a = p[0], b = p[1];
                v[0] = a.x; v[1] = a.y; v[2] = a.z; v[3] = a.w;
                v[4] = b.x; v[5] = b.y; v[6] = b.z; v[7] = b.w;
            } else {
#pragma unroll
                for (int j = 0; j < 8; ++j) v[j] = 0.f;
            }
#pragma unroll
            for (int j = 0; j < 8; ++j) {
                ushort_t h = f2bf(v[j]);
                Ah[ks][j] = (short)h;
                Al[ks][j] = (short)f2bf(v[j] - bf2f(h));
            }
        }
    };
    auto loadA_lds = [&]() {
#pragma unroll
        for (int ks = 0; ks < 4; ++ks) {
            if (l15 < 8) {
                const char* base = (const char*)&tsh[l15][0] + (ks << 6) + (l4 << 4);
                Ah[ks] = *(const bf16x8*)base;
                const char* basel = (const char*)&tsl[l15][0] + (ks << 6) + (l4 << 4);
                Al[ks] = *(const bf16x8*)basel;
            } else {
#pragma unroll
                for (int j = 0; j < 8; ++j) { Ah[ks][j] = 0; Al[ks][j] = 0; }
            }
        }
    };

    if (mode & 1) {
        loadA_global(agg);
        float bfv = bfv_g[fcol];
        f32x4 acc = {bfv, bfv, bfv, bfv};
#pragma unroll
        for (int ks = 0; ks < 4; ++ks) {
            const bf16x8 Bh = *(const bf16x8*)(wfh + ((size_t)fcol << 7) + (ks << 5) + (l4 << 3));
            const bf16x8 Bl = *(const bf16x8*)(wfl + ((size_t)fcol << 7) + (ks << 5) + (l4 << 3));
            acc = __builtin_amdgcn_mfma_f32_16x16x32_bf16(Al[ks], Bh, acc, 0, 0, 0);
            acc = __builtin_amdgcn_mfma_f32_16x16x32_bf16(Ah[ks], Bl, acc, 0, 0, 0);
            acc = __builtin_amdgcn_mfma_f32_16x16x32_bf16(Ah[ks], Bh, acc, 0, 0, 0);
        }
#pragma unroll
        for (int reg = 0; reg < 4; ++reg) {
            int r = (l4 << 2) + reg;
            if (r < 8) {
                float v = ssp_f(acc[reg]);
                ushort_t h = f2bf(v);
                tsh[r][fcol] = h;
                tsl[r][fcol] = f2bf(v - bf2f(h));
            }
        }
        __syncthreads();
        loadA_lds();
        float bdv = bdv_g[fcol];
        f32x4 acc2 = {bdv, bdv, bdv, bdv};
#pragma unroll
        for (int ks = 0; ks < 4; ++ks) {
            const bf16x8 Bh = *(const bf16x8*)(wdh + ((size_t)fcol << 7) + (ks << 5) + (l4 << 3));
            const bf16x8 Bl = *(const bf16x8*)(wdl + ((size_t)fcol << 7) + (ks << 5) + (l4 << 3));
            acc2 = __builtin_amdgcn_mfma_f32_16x16x32_bf16(Al[ks], Bh, acc2, 0, 0, 0);
            acc2 = __builtin_amdgcn_mfma_f32_16x16x32_bf16(Ah[ks], Bl, acc2, 0, 0, 0);
            acc2 = __builtin_amdgcn_mfma_f32_16x16x32_bf16(Ah[ks], Bh, acc2, 0, 0, 0);
        }
        __syncthreads();
#pragma unroll
        for (int reg = 0; reg < 4; ++reg) {
            int r = (l4 << 2) + reg;
            if (r < 8) {
                size_t gi = ((size_t)(r0 + r) << 7) + fcol;
                float xn = x_in[gi] + acc2[reg];
                x_out[gi] = xn;
                if (mode & 4) out[gi] = xn;
                if (mode & 2) {
                    ushort_t h = f2bf(xn);
                    tsh[r][fcol] = h;
                    tsl[r][fcol] = f2bf(xn - bf2f(h));
                }
            }
        }
        if (mode & 2) __syncthreads();
    }
    if (mode & 2) {
        if (mode & 1) loadA_lds(); else loadA_global(x_in);
        f32x4 acc3 = {0.f, 0.f, 0.f, 0.f};
#pragma unroll
        for (int ks = 0; ks < 4; ++ks) {
            const bf16x8 Bh = *(const bf16x8*)(wih + ((size_t)fcol << 7) + (ks << 5) + (l4 << 3));
            const bf16x8 Bl = *(const bf16x8*)(wil + ((size_t)fcol << 7) + (ks << 5) + (l4 << 3));
            acc3 = __builtin_amdgcn_mfma_f32_16x16x32_bf16(Al[ks], Bh, acc3, 0, 0, 0);
            acc3 = __builtin_amdgcn_mfma_f32_16x16x32_bf16(Ah[ks], Bl, acc3, 0, 0, 0);
            acc3 = __builtin_amdgcn_mfma_f32_16x16x32_bf16(Ah[ks], Bh, acc3, 0, 0, 0);
        }
#pragma unroll
        for (int reg = 0; reg < 4; ++reg) {
            int r = (l4 << 2) + reg;
            if (r < 8) y[((size_t)(r0 + r) << 7) + fcol] = acc3[reg];
        }
    }
}

// LDS layout (dynamic, 34304 B):
//  [0,32768)      h bf16 [128n][128f], swizzled: byte = n*256 + ((f*2) ^ ((n&7)<<4))
//  [0,4096)       (post-phase2 alias) red: 8 waves x 128 f32, swizzled
//  [32768,33280)  cm f32[128]; [33280,33792) nbr i32[128]; [33792,34304) r f32[128]
#define SMEM_BYTES 34304

__global__ __launch_bounds__(512, 6) void k_cfconv(
    const float* __restrict__ r_g, const float* __restrict__ cm_g,
    const int* __restrict__ neighbors,
    const ushort_t* __restrict__ w1t, const float* __restrict__ b1,
    const ushort_t* __restrict__ w2f, const float* __restrict__ b2,
    const float* __restrict__ y, float* __restrict__ agg) {
    extern __shared__ char smem[];
    float* cm_s = (float*)(smem + 32768);
    int* nbr_s = (int*)(smem + 33280);
    float* r_s = (float*)(smem + 33792);
    float* red_s = (float*)smem;

    const int row = blockIdx.x;
    const int b = row >> 7;
    const int t = threadIdx.x;
    const int lane = t & 63, w = t >> 6;       // 8 waves
    const int l15 = lane & 15, l4 = lane >> 4;
    const int wr = w >> 2, wc = w & 3;

    // -- phase 0a: load precomputed geometry (coalesced) --
    if (t < 128) {
        r_s[t] = r_g[((size_t)row << 7) + t];
        cm_s[t] = cm_g[((size_t)row << 7) + t];
        nbr_s[t] = (t < NNB) ? neighbors[row * NNB + t] : 0;
    }
    __syncthreads();   // (1) r_s, cm_s, nbr_s ready

    // -- phase 1: fij in registers; D[f][n] = W1T * fijT; ssp; b64 swizzled h write --
    {
        const int nrow = (w << 4) + l15;
        const float rv = r_s[nrow];
        const float width = 5.0f / (GG - 1);
        const float coeff = -0.5f / (width * width);
        float fv[8];
#pragma unroll
        for (int j = 0; j < 8; ++j) {
            int g = (l4 << 3) + j;
            float d = rv - g * width;
            fv[j] = (g < GG) ? __expf(coeff * d * d) : 0.f;
        }
        bf16x8 fb;
        unsigned int* fbu = (unsigned int*)&fb;
        fbu[0] = pack2bf_rhu(fv[0], fv[1]);
        fbu[1] = pack2bf_rhu(fv[2], fv[3]);
        fbu[2] = pack2bf_rhu(fv[4], fv[5]);
        fbu[3] = pack2bf_rhu(fv[6], fv[7]);
        const int base = nrow * 256;
        const int sw = (nrow & 7) << 4;
#pragma unroll
        for (int ft = 0; ft < 8; ++ft) {
            bf16x8 aw = *(const bf16x8*)(w1t + ((ft << 4) + l15) * 32 + (l4 << 3));
            const int f0 = (ft << 4) + (l4 << 2);
            f32x4 c0 = *(const f32x4*)(b1 + f0);
            f32x4 d = __builtin_amdgcn_mfma_f32_16x16x32_bf16(aw, fb, c0, 0, 0, 0);
            unsigned int lo32 = pack2bf_rhu(ssp_fast(d[0]), ssp_fast(d[1]));
            unsigned int hi32 = pack2bf_rhu(ssp_fast(d[2]), ssp_fast(d[3]));
            unsigned long long pk = (unsigned long long)lo32 | ((unsigned long long)hi32 << 32);
            *(unsigned long long*)(smem + base + ((f0 << 1) ^ sw)) = pk;
        }
    }

    // issue first W2 fragment loads before the barrier (independent of LDS)
#define W2LD(ks, ft) (*(const bf16x8*)(w2f + (((((ks) << 3) + (wc << 1) + (ft)) << 6) + lane) * 8))
    bf16x8 wb0 = W2LD(0, 0), wb1 = W2LD(0, 1);
    __syncthreads();   // (2) h ready

    // -- phase 2: wave (wr,wc) = 64n x 32f; B-frags prefetched from global/L2 --
    f32x4 acc[4][2];
#pragma unroll
    for (int mi = 0; mi < 4; ++mi)
#pragma unroll
        for (int ft = 0; ft < 2; ++ft) {
            float b2v = b2[(wc << 5) + (ft << 4) + l15];
            f32x4 c0 = {b2v, b2v, b2v, b2v};
            acc[mi][ft] = c0;
        }
#pragma unroll
    for (int ks = 0; ks < 4; ++ks) {
        bf16x8 wn0, wn1;
        if (ks < 3) { wn0 = W2LD(ks + 1, 0); wn1 = W2LD(ks + 1, 1); }
        bf16x8 ha[4];
#pragma unroll
        for (int mi = 0; mi < 4; ++mi) {
            int n = (wr << 6) + (mi << 4) + l15;
            ha[mi] = *(const bf16x8*)(smem + n * 256 + ((((ks << 2) + l4) << 4) ^ ((n & 7) << 4)));
        }
#pragma unroll
        for (int mi = 0; mi < 4; ++mi) {
            acc[mi][0] = __builtin_amdgcn_mfma_f32_16x16x32_bf16(ha[mi], wb0, acc[mi][0], 0, 0, 0);
            acc[mi][1] = __builtin_amdgcn_mfma_f32_16x16x32_bf16(ha[mi], wb1, acc[mi][1], 0, 0, 0);
        }
        if (ks < 3) { wb0 = wn0; wb1 = wn1; }
    }
#undef W2LD
    __syncthreads();   // (3) all h reads done; red region safe

    // -- epilogue: gather y rows directly from L2; part += y * (acc * cm) --
    float part0 = 0.f, part1 = 0.f;
    const float* ybase = y + ((size_t)(b * AA) << 7) + (wc << 5) + l15;
#pragma unroll
    for (int mi = 0; mi < 4; ++mi) {
        float yv0[4], yv1[4], cmv[4];
#pragma unroll
        for (int r = 0; r < 4; ++r) {
            int n = (wr << 6) + (mi << 4) + (l4 << 2) + r;
            int nb = nbr_s[n];
            cmv[r] = cm_s[n];
            const float* yr = ybase + ((size_t)nb << 7);
            yv0[r] = yr[0];
            yv1[r] = yr[16];
        }
#pragma unroll
        for (int r = 0; r < 4; ++r) {
            part0 = fmaf(yv0[r], acc[mi][0][r] * cmv[r], part0);
            part1 = fmaf(yv1[r], acc[mi][1][r] * cmv[r], part1);
        }
    }
    {
        int xg = l4 << 3;
        red_s[(w << 7) + (l4 << 5) + (l15 ^ xg)] = part0;
        red_s[(w << 7) + (l4 << 5) + ((16 + l15) ^ xg)] = part1;
    }
    __syncthreads();   // (4)
    if (t < FF) {
        int wcf = t >> 5, fl = t & 31;
        float s = 0.f;
#pragma unroll
        for (int wr2 = 0; wr2 < 2; ++wr2)
#pragma unroll
            for (int g = 0; g < 4; ++g)
                s += red_s[(((wr2 << 2) + wcf) << 7) + (g << 5) + (fl ^ (g << 3))];
        agg[(size_t)row * FF + t] = s;
    }
}

extern "C" void kernel_launch(void* const* d_in, const int* in_sizes, int n_in,
                              void* d_out, int out_size, void* d_ws, size_t ws_size,
                              hipStream_t stream) {
    const float* positions   = (const float*)d_in[0];
    const float* cell        = (const float*)d_in[1];
    const float* cell_offset = (const float*)d_in[2];
    const float* nmask       = (const float*)d_in[3];
    const float* emb         = (const float*)d_in[4];
    const float* filt_W1     = (const float*)d_in[5];
    const float* filt_b1     = (const float*)d_in[6];
    const float* filt_W2     = (const float*)d_in[7];
    const float* filt_b2     = (const float*)d_in[8];
    const float* in2f_W      = (const float*)d_in[9];
    const float* f2out_W     = (const float*)d_in[10];
    const float* f2out_b     = (const float*)d_in[11];
    const float* dense_W     = (const float*)d_in[12];
    const float* dense_b     = (const float*)d_in[13];
    const int* atomic_numbers = (const int*)d_in[14];
    const int* neighbors      = (const int*)d_in[15];
    float* out = (float*)d_out;

    float* x    = (float*)d_ws;                        // 262144 f32
    float* yb   = x + BB * AA * FF;                    // 262144 f32
    float* agg  = yb + BB * AA * FF;                   // 262144 f32
    float* r_g  = agg + BB * AA * FF;                  // 262144 f32
    float* cm_g = r_g + BB * AA * 128;                 // 262144 f32
    ushort_t* w1t = (ushort_t*)(cm_g + BB * AA * 128); // 12288 u16
    ushort_t* w2f = w1t + 3 * 128 * 32;                // 49152 u16
    ushort_t* whi = w2f + 3 * 16384;                   // 147456 u16
    ushort_t* wlo = whi + 9 * 16384;                   // 147456 u16

    k_geom<<<(BB * AA * 128 + 255) / 256, 256, 0, stream>>>(positions, cell, cell_offset,
                                                            nmask, neighbors, r_g, cm_g);
    k_prep<<<576, 256, 0, stream>>>(filt_W1, filt_W2, in2f_W, f2out_W, dense_W,
                                    w1t, w2f, whi, wlo);
    k_init_x<<<(BB * AA * FF + 255) / 256, 256, 0, stream>>>(emb, atomic_numbers, x);

    // y0 = x @ in2f_W[0]  (G3-only)
    k_ffn<<<256, 512, 0, stream>>>(x, x, x, yb, out,
                                   whi + 3 * 16384, wlo + 3 * 16384, f2out_b,
                                   whi + 6 * 16384, wlo + 6 * 16384, dense_b,
                                   whi + 0 * 16384, wlo + 0 * 16384,
                                   2);
    for (int l = 0; l < 3; ++l) {
        k_cfconv<<<BB * AA, 512, SMEM_BYTES, stream>>>(
            r_g, cm_g, neighbors,
            w1t + (size_t)l * 128 * 32, filt_b1 + (size_t)l * FF,
            w2f + (size_t)l * 16384, filt_b2 + (size_t)l * FF,
            yb, agg);
        int nextl = (l < 2) ? (l + 1) : 0;
        int mode = 1 | ((l < 2) ? 2 : 0) | ((l == 2) ? 4 : 0);
        k_ffn<<<256, 512, 0, stream>>>(agg, x, x, yb, out,
                                       whi + (3 + l) * 16384, wlo + (3 + l) * 16384, f2out_b + (size_t)l * FF,
                                       whi + (6 + l) * 16384, wlo + (6 + l) * 16384, dense_b + (size_t)l * FF,
                                       whi + nextl * 16384, wlo + nextl * 16384,
                                       mode);
    }
}